// Round 9
// baseline (2165.725 us; speedup 1.0000x reference)
//
#include <hip/hip_runtime.h>
#include <hip/hip_bf16.h>

// Problem: L=D=H=512 self-matching additive attention + bidirectional GRU.
// Inputs f32 (13 tensors), output f32 [512, 1024] = [hf | hb].

#define L 512
#define DD 512
#define HH 512

__device__ __forceinline__ float tanhf_fast(float x) {
    float ex = __expf(2.f * x);
    return 1.f - __fdividef(2.f, ex + 1.f);
}

__device__ __forceinline__ float sigmoidf_fast(float x) {
    return __fdividef(1.f, 1.f + __expf(-x));
}

// ---------------- GEMM body: C[M,N] = A[M,K] * op(B) + bias ----------------
template <int BT>
__device__ __forceinline__ void gemm_body(
    const float* __restrict__ A, const float* __restrict__ B,
    const float* __restrict__ bias, float* __restrict__ C,
    int M, int N, int K)
{
    __shared__ float As[16][68];
    __shared__ float Bs[16][68];
    int tid = threadIdx.x;
    int m0 = blockIdx.y * 64, n0 = blockIdx.x * 64;
    int tm = (tid & 15) * 4;
    int tn = (tid >> 4) * 4;
    float acc[4][4] = {};

    for (int k0 = 0; k0 < K; k0 += 16) {
        {
            int c = tid & 15, r0 = tid >> 4;
#pragma unroll
            for (int q = 0; q < 4; q++) {
                int r = r0 + q * 16;
                As[c][r] = A[(size_t)(m0 + r) * K + k0 + c];
            }
        }
        if (BT) {
            int c = tid & 15, r0 = tid >> 4;
#pragma unroll
            for (int q = 0; q < 4; q++) {
                int n = r0 + q * 16;
                Bs[c][n] = B[(size_t)(n0 + n) * K + k0 + c];
            }
        } else {
            int n = tid & 63, r0 = tid >> 6;
#pragma unroll
            for (int q = 0; q < 4; q++) {
                int k = r0 + q * 4;
                Bs[k][n] = B[(size_t)(k0 + k) * N + n0 + n];
            }
        }
        __syncthreads();
#pragma unroll
        for (int k = 0; k < 16; k++) {
            float4 av = *(const float4*)&As[k][tm];
            float4 bv = *(const float4*)&Bs[k][tn];
            float a[4] = {av.x, av.y, av.z, av.w};
            float b[4] = {bv.x, bv.y, bv.z, bv.w};
#pragma unroll
            for (int i = 0; i < 4; i++)
#pragma unroll
                for (int j = 0; j < 4; j++) acc[i][j] += a[i] * b[j];
        }
        __syncthreads();
    }
#pragma unroll
    for (int i = 0; i < 4; i++) {
        float4 o;
        o.x = acc[i][0] + (bias ? bias[n0 + tn + 0] : 0.f);
        o.y = acc[i][1] + (bias ? bias[n0 + tn + 1] : 0.f);
        o.z = acc[i][2] + (bias ? bias[n0 + tn + 2] : 0.f);
        o.w = acc[i][3] + (bias ? bias[n0 + tn + 3] : 0.f);
        *(float4*)&C[(size_t)(m0 + tm + i) * N + n0 + tn] = o;
    }
}

template <int BT>
__global__ __launch_bounds__(256) void gemm_k(
    const float* __restrict__ A, const float* __restrict__ B,
    const float* __restrict__ bias, float* __restrict__ C,
    int M, int N, int K)
{
    gemm_body<BT>(A, B, bias, C, M, N, K);
}

template <int BT>
__global__ __launch_bounds__(256) void gemm2_k(
    const float* __restrict__ A,
    const float* __restrict__ B0, const float* __restrict__ B1,
    const float* __restrict__ bias0, const float* __restrict__ bias1,
    float* __restrict__ C0, float* __restrict__ C1,
    int M, int N, int K)
{
    if (blockIdx.z == 0) gemm_body<BT>(A, B0, bias0, C0, M, N, K);
    else                 gemm_body<BT>(A, B1, bias1, C1, M, N, K);
}

// gi GEMM with fused concat: A = [v | c] (virtual [512,1024]), B^T layout.
__global__ __launch_bounds__(256) void gemm_gi_k(
    const float* __restrict__ v, const float* __restrict__ cc_,
    const float* __restrict__ B0, const float* __restrict__ B1,
    const float* __restrict__ bias0, const float* __restrict__ bias1,
    float* __restrict__ C0, float* __restrict__ C1)
{
    const float* B    = blockIdx.z ? B1 : B0;
    const float* bias = blockIdx.z ? bias1 : bias0;
    float* C          = blockIdx.z ? C1 : C0;
    const int N = 1536, K = 1024;

    __shared__ float As[16][68];
    __shared__ float Bs[16][68];
    int tid = threadIdx.x;
    int m0 = blockIdx.y * 64, n0 = blockIdx.x * 64;
    int tm = (tid & 15) * 4;
    int tn = (tid >> 4) * 4;
    float acc[4][4] = {};

    for (int k0 = 0; k0 < K; k0 += 16) {
        const float* Asrc = (k0 < 512) ? v : cc_;
        int koff = (k0 < 512) ? k0 : (k0 - 512);
        {
            int c = tid & 15, r0 = tid >> 4;
#pragma unroll
            for (int q = 0; q < 4; q++) {
                int r = r0 + q * 16;
                As[c][r] = Asrc[(size_t)(m0 + r) * 512 + koff + c];
            }
        }
        {
            int c = tid & 15, r0 = tid >> 4;
#pragma unroll
            for (int q = 0; q < 4; q++) {
                int n = r0 + q * 16;
                Bs[c][n] = B[(size_t)(n0 + n) * K + k0 + c];
            }
        }
        __syncthreads();
#pragma unroll
        for (int k = 0; k < 16; k++) {
            float4 av = *(const float4*)&As[k][tm];
            float4 bv = *(const float4*)&Bs[k][tn];
            float a[4] = {av.x, av.y, av.z, av.w};
            float b[4] = {bv.x, bv.y, bv.z, bv.w};
#pragma unroll
            for (int i = 0; i < 4; i++)
#pragma unroll
                for (int j = 0; j < 4; j++) acc[i][j] += a[i] * b[j];
        }
        __syncthreads();
    }
#pragma unroll
    for (int i = 0; i < 4; i++) {
        float4 o;
        o.x = acc[i][0] + bias[n0 + tn + 0];
        o.y = acc[i][1] + bias[n0 + tn + 1];
        o.z = acc[i][2] + bias[n0 + tn + 2];
        o.w = acc[i][3] + bias[n0 + tn + 3];
        *(float4*)&C[(size_t)(m0 + tm + i) * N + n0 + tn] = o;
    }
}

// ---------------- attention scores ----------------
__global__ __launch_bounds__(256) void attn_e_k(
    const float* __restrict__ u, const float* __restrict__ w,
    const float* __restrict__ v, float* __restrict__ e)
{
    __shared__ float wS[16][68];
    __shared__ float uS[32][68];
    __shared__ float vS[32][68];
    int tid = threadIdx.x;
    int t0 = blockIdx.y * 16, j0 = blockIdx.x * 32;
    int tt = tid >> 5, jj = tid & 31;
    float acc0 = 0.f, acc1 = 0.f;

    for (int d0 = 0; d0 < DD; d0 += 64) {
        {
            int c = tid & 63, r0 = tid >> 6;
#pragma unroll
            for (int q = 0; q < 4; q++)
                wS[r0 + q * 4][c] = w[(size_t)(t0 + r0 + q * 4) * DD + d0 + c];
#pragma unroll
            for (int q = 0; q < 8; q++) {
                int r = r0 + q * 4;
                uS[r][c] = u[(size_t)(j0 + r) * DD + d0 + c];
                vS[r][c] = v[(size_t)(j0 + r) * DD + d0 + c];
            }
        }
        __syncthreads();
#pragma unroll
        for (int c4 = 0; c4 < 16; c4++) {
            float4 uv = *(const float4*)&uS[jj][c4 * 4];
            float4 vv = *(const float4*)&vS[jj][c4 * 4];
            float4 w0 = *(const float4*)&wS[tt][c4 * 4];
            float4 w1 = *(const float4*)&wS[tt + 8][c4 * 4];
            acc0 += tanhf_fast(uv.x + w0.x) * vv.x;
            acc0 += tanhf_fast(uv.y + w0.y) * vv.y;
            acc0 += tanhf_fast(uv.z + w0.z) * vv.z;
            acc0 += tanhf_fast(uv.w + w0.w) * vv.w;
            acc1 += tanhf_fast(uv.x + w1.x) * vv.x;
            acc1 += tanhf_fast(uv.y + w1.y) * vv.y;
            acc1 += tanhf_fast(uv.z + w1.z) * vv.z;
            acc1 += tanhf_fast(uv.w + w1.w) * vv.w;
        }
        __syncthreads();
    }
    e[(size_t)(t0 + tt) * L + j0 + jj] = acc0;
    e[(size_t)(t0 + tt + 8) * L + j0 + jj] = acc1;
}

// ---------------- row softmax (in place) ----------------
__global__ __launch_bounds__(256) void softmax_k(float* __restrict__ e) {
    int t = blockIdx.x;
    float* row = e + (size_t)t * L;
    int tid = threadIdx.x;
    float v0 = row[tid], v1 = row[tid + 256];
    float m = fmaxf(v0, v1);
#pragma unroll
    for (int off = 32; off > 0; off >>= 1) m = fmaxf(m, __shfl_xor(m, off));
    __shared__ float red[4];
    __shared__ float red2[4];
    int wid = tid >> 6, lane = tid & 63;
    if (lane == 0) red[wid] = m;
    __syncthreads();
    m = fmaxf(fmaxf(red[0], red[1]), fmaxf(red[2], red[3]));
    float e0 = __expf(v0 - m), e1 = __expf(v1 - m);
    float s = e0 + e1;
#pragma unroll
    for (int off = 32; off > 0; off >>= 1) s += __shfl_xor(s, off);
    if (lane == 0) red2[wid] = s;
    __syncthreads();
    s = red2[0] + red2[1] + red2[2] + red2[3];
    float inv = __fdividef(1.f, s);
    row[tid] = e0 * inv;
    row[tid + 256] = e1 * inv;
}

// ---------------- GRU scan: 16 blocks/dir x 512 threads, 32 h per block ----
// Wave w (of 8) owns 12 of the block's 96 whh rows; lane owns 8 columns
// (96 VGPR of weights). Matvec: lanes read their h-slice from LDS, butterfly
// shfl-reduce 12 sums, lanes<12 write ghS[w*12+lane]. Wave 0 then computes
// all 32 gates (h_prev lane-local), fires the 128B tagged store (merged
// 24-bit fixed point + 8-bit step tag words), and is the ONLY poller: its 64
// lanes poll 4 sticky u64 pairs each (covers all 512 words), decode into LDS
// hS. Other waves wait at the barrier => pollers/dir = 16 waves (was 256).
// gi prefetch for step s+1 issues at the TOP of step s so the poll's
// vmcnt(0) drain never waits on HBM. Parity ping-pong + skew<=1 + tag mod
// 256 => no aliasing; 0xAA poison can't match tags 1/2 => no memset.
__global__ __launch_bounds__(512) void gru_scan_k(
    const float* __restrict__ whh_f, const float* __restrict__ bhh_f,
    const float* __restrict__ whh_b, const float* __restrict__ bhh_b,
    const float* __restrict__ gi_f, const float* __restrict__ gi_b,
    float* __restrict__ out,
    unsigned* __restrict__ hstage)   // [2 dirs][2 parity][512] encoded u32
{
    int blk = blockIdx.x;            // 0..31
    int dir = blk >> 4;              // 0 fwd, 1 bwd
    int bi  = blk & 15;
    int hbase = bi * 32;
    const float* whh = dir ? whh_b : whh_f;
    const float* bhh = dir ? bhh_b : bhh_f;
    const float* gi  = dir ? gi_b : gi_f;
    float* outBase = out + dir * HH;       // row stride 1024
    unsigned* stage = hstage + dir * 1024;

    __shared__ float hS[HH];
    __shared__ float ghS[96];

    int tid = threadIdx.x;
    int wv = tid >> 6;               // 0..7
    int lane = tid & 63;

    // wave wv owns block-local rows [wv*12, wv*12+12); row r -> (g=r>>5, i=r&31)
    // -> whh row g*512 + hbase + i. Lane owns cols [lane*8, lane*8+8).
    float4 wa[12], wb[12];
#pragma unroll
    for (int q = 0; q < 12; q++) {
        int r = wv * 12 + q;
        int g = r >> 5, i = r & 31;
        const float* row = whh + (size_t)(g * HH + hbase + i) * HH + lane * 8;
        wa[q] = *(const float4*)row;
        wb[q] = *(const float4*)(row + 4);
    }

    float bhr = 0.f, bhz = 0.f, bhn = 0.f, hp = 0.f;
    float ir = 0.f, iz = 0.f, inn = 0.f;
    float ir2 = 0.f, iz2 = 0.f, inn2 = 0.f;
    if (wv == 0 && lane < 32) {
        bhr = bhh[0 * HH + hbase + lane];
        bhz = bhh[1 * HH + hbase + lane];
        bhn = bhh[2 * HH + hbase + lane];
        int t0 = dir ? (L - 1) : 0;
        const float* git = gi + (size_t)t0 * (3 * HH);
        ir  = git[hbase + lane];
        iz  = git[HH + hbase + lane];
        inn = git[2 * HH + hbase + lane];
    }
    if (tid < 512) hS[tid] = 0.f;
    __syncthreads();

    const float ENC = 4194304.0f;            // 2^22
    const float DEC = 1.0f / 4194304.0f;

    for (int s = 0; s < L; s++) {
        int t = dir ? (L - 1 - s) : s;

        // issue NEXT step's gi loads now (lands during matvec; poll's
        // vmcnt(0) then doesn't wait on HBM)
        if (wv == 0 && lane < 32 && s < L - 1) {
            int tn = dir ? (L - 2 - s) : (s + 1);
            const float* git = gi + (size_t)tn * (3 * HH);
            ir2  = git[hbase + lane];
            iz2  = git[HH + hbase + lane];
            inn2 = git[2 * HH + hbase + lane];
        }

        // matvec: 12 rows x lane's 8 h-columns
        float4 h0 = *(const float4*)(hS + lane * 8);
        float4 h1 = *(const float4*)(hS + lane * 8 + 4);
        float acc[12];
#pragma unroll
        for (int q = 0; q < 12; q++) {
            acc[q] = wa[q].x * h0.x + wa[q].y * h0.y + wa[q].z * h0.z + wa[q].w * h0.w
                   + wb[q].x * h1.x + wb[q].y * h1.y + wb[q].z * h1.z + wb[q].w * h1.w;
        }
#pragma unroll
        for (int off = 32; off > 0; off >>= 1) {
#pragma unroll
            for (int q = 0; q < 12; q++) acc[q] += __shfl_xor(acc[q], off);
        }
        if (lane < 12) ghS[wv * 12 + lane] = acc[lane];
        __syncthreads();

        if (wv == 0) {
            if (lane < 32) {
                float r = sigmoidf_fast(ir + ghS[lane] + bhr);
                float z = sigmoidf_fast(iz + ghS[32 + lane] + bhz);
                float n = tanhf_fast(inn + r * (ghS[64 + lane] + bhn));
                float hnew = (1.f - z) * n + z * hp;
                hp = hnew;
                unsigned enc = ((unsigned)__float2int_rn(hnew * ENC) & 0x00FFFFFFu)
                             | ((unsigned)((s + 1) & 0xFF) << 24);
                __hip_atomic_store(stage + (s & 1) * 512 + hbase + lane, enc,
                                   __ATOMIC_RELAXED, __HIP_MEMORY_SCOPE_AGENT);
                outBase[(size_t)t * 1024 + hbase + lane] = hnew;
            }
            ir = ir2; iz = iz2; inn = inn2;

            if (s < L - 1) {
                // sole poller: 4 sticky u64 pairs per lane covers 512 words
                unsigned tag = (unsigned)((s + 1) & 0xFF);
                const unsigned long long* src =
                    (const unsigned long long*)(stage + (s & 1) * 512);
                unsigned long long p0 = 0, p1 = 0, p2 = 0, p3 = 0;
                bool k0 = false, k1 = false, k2 = false, k3 = false;
                do {
                    if (!k0) {
                        p0 = __hip_atomic_load(src + lane, __ATOMIC_RELAXED,
                                               __HIP_MEMORY_SCOPE_AGENT);
                        k0 = (((unsigned)(p0 >> 24) & 0xFF) == tag) && ((unsigned)(p0 >> 56) == tag);
                    }
                    if (!k1) {
                        p1 = __hip_atomic_load(src + lane + 64, __ATOMIC_RELAXED,
                                               __HIP_MEMORY_SCOPE_AGENT);
                        k1 = (((unsigned)(p1 >> 24) & 0xFF) == tag) && ((unsigned)(p1 >> 56) == tag);
                    }
                    if (!k2) {
                        p2 = __hip_atomic_load(src + lane + 128, __ATOMIC_RELAXED,
                                               __HIP_MEMORY_SCOPE_AGENT);
                        k2 = (((unsigned)(p2 >> 24) & 0xFF) == tag) && ((unsigned)(p2 >> 56) == tag);
                    }
                    if (!k3) {
                        p3 = __hip_atomic_load(src + lane + 192, __ATOMIC_RELAXED,
                                               __HIP_MEMORY_SCOPE_AGENT);
                        k3 = (((unsigned)(p3 >> 24) & 0xFF) == tag) && ((unsigned)(p3 >> 56) == tag);
                    }
                } while (!__all(k0 && k1 && k2 && k3));

                {
                    unsigned e0, e1;
                    float2 hv;
                    e0 = (unsigned)p0; e1 = (unsigned)(p0 >> 32);
                    hv.x = (float)(((int)(e0 << 8)) >> 8) * DEC;
                    hv.y = (float)(((int)(e1 << 8)) >> 8) * DEC;
                    *(float2*)&hS[2 * lane] = hv;
                    e0 = (unsigned)p1; e1 = (unsigned)(p1 >> 32);
                    hv.x = (float)(((int)(e0 << 8)) >> 8) * DEC;
                    hv.y = (float)(((int)(e1 << 8)) >> 8) * DEC;
                    *(float2*)&hS[2 * (lane + 64)] = hv;
                    e0 = (unsigned)p2; e1 = (unsigned)(p2 >> 32);
                    hv.x = (float)(((int)(e0 << 8)) >> 8) * DEC;
                    hv.y = (float)(((int)(e1 << 8)) >> 8) * DEC;
                    *(float2*)&hS[2 * (lane + 128)] = hv;
                    e0 = (unsigned)p3; e1 = (unsigned)(p3 >> 32);
                    hv.x = (float)(((int)(e0 << 8)) >> 8) * DEC;
                    hv.y = (float)(((int)(e1 << 8)) >> 8) * DEC;
                    *(float2*)&hS[2 * (lane + 192)] = hv;
                }
            }
        }
        __syncthreads();
    }
}

extern "C" void kernel_launch(void* const* d_in, const int* in_sizes, int n_in,
                              void* d_out, int out_size, void* d_ws, size_t ws_size,
                              hipStream_t stream) {
    const float* v     = (const float*)d_in[0];
    const float* w1    = (const float*)d_in[1];
    const float* b1    = (const float*)d_in[2];
    const float* w2    = (const float*)d_in[3];
    const float* b2    = (const float*)d_in[4];
    const float* wih_f = (const float*)d_in[5];
    const float* whh_f = (const float*)d_in[6];
    const float* bih_f = (const float*)d_in[7];
    const float* bhh_f = (const float*)d_in[8];
    const float* wih_b = (const float*)d_in[9];
    const float* whh_b = (const float*)d_in[10];
    const float* bih_b = (const float*)d_in[11];
    const float* bhh_b = (const float*)d_in[12];
    float* out = (float*)d_out;   // f32 [512, 1024]

    float* ws = (float*)d_ws;
    float* u   = ws;                 // 512*512
    float* w_  = ws + 262144;        // 512*512
    float* e   = ws + 524288;        // 512*512 (becomes a after softmax)
    float* c   = ws + 786432;        // 512*512
    float* gif = ws + 1572864;       // 512*1536
    float* gib = ws + 2359296;       // 512*1536
    unsigned* hstage = (unsigned*)(ws + 3145728);  // 2*2*512 u32 (no init needed)

    // u = v @ w1^T + b1 ; w = v @ w2^T + b2  (one launch, z selects)
    gemm2_k<1><<<dim3(8, 8, 2), 256, 0, stream>>>(v, w1, w2, b1, b2, u, w_,
                                                  512, 512, 512);

    // e[t,j] = sum_d tanh(u[j,d]+w[t,d]) v[j,d]
    attn_e_k<<<dim3(16, 32), 256, 0, stream>>>(u, w_, v, e);
    softmax_k<<<512, 256, 0, stream>>>(e);

    // c = a @ v
    gemm_k<0><<<dim3(8, 8), 256, 0, stream>>>(e, v, nullptr, c, 512, 512, 512);

    // gi = [v|c] @ wih^T + bih, both directions, concat fused into A-load
    gemm_gi_k<<<dim3(24, 8, 2), 256, 0, stream>>>(v, c, wih_f, wih_b,
                                                  bih_f, bih_b, gif, gib);

    gru_scan_k<<<32, 512, 0, stream>>>(whh_f, bhh_f, whh_b, bhh_b,
                                       gif, gib, out, hstage);
}

// Round 10
// 1340.709 us; speedup vs baseline: 1.6154x; 1.6154x over previous
//
#include <hip/hip_runtime.h>
#include <hip/hip_bf16.h>

// Problem: L=D=H=512 self-matching additive attention + bidirectional GRU.
// Inputs f32 (13 tensors), output f32 [512, 1024] = [hf | hb].

#define L 512
#define DD 512
#define HH 512

__device__ __forceinline__ float tanhf_fast(float x) {
    float ex = __expf(2.f * x);
    return 1.f - __fdividef(2.f, ex + 1.f);
}

__device__ __forceinline__ float sigmoidf_fast(float x) {
    return __fdividef(1.f, 1.f + __expf(-x));
}

// ---------------- GEMM body: C[M,N] = A[M,K] * op(B) + bias ----------------
template <int BT>
__device__ __forceinline__ void gemm_body(
    const float* __restrict__ A, const float* __restrict__ B,
    const float* __restrict__ bias, float* __restrict__ C,
    int M, int N, int K)
{
    __shared__ float As[16][68];
    __shared__ float Bs[16][68];
    int tid = threadIdx.x;
    int m0 = blockIdx.y * 64, n0 = blockIdx.x * 64;
    int tm = (tid & 15) * 4;
    int tn = (tid >> 4) * 4;
    float acc[4][4] = {};

    for (int k0 = 0; k0 < K; k0 += 16) {
        {
            int c = tid & 15, r0 = tid >> 4;
#pragma unroll
            for (int q = 0; q < 4; q++) {
                int r = r0 + q * 16;
                As[c][r] = A[(size_t)(m0 + r) * K + k0 + c];
            }
        }
        if (BT) {
            int c = tid & 15, r0 = tid >> 4;
#pragma unroll
            for (int q = 0; q < 4; q++) {
                int n = r0 + q * 16;
                Bs[c][n] = B[(size_t)(n0 + n) * K + k0 + c];
            }
        } else {
            int n = tid & 63, r0 = tid >> 6;
#pragma unroll
            for (int q = 0; q < 4; q++) {
                int k = r0 + q * 4;
                Bs[k][n] = B[(size_t)(k0 + k) * N + n0 + n];
            }
        }
        __syncthreads();
#pragma unroll
        for (int k = 0; k < 16; k++) {
            float4 av = *(const float4*)&As[k][tm];
            float4 bv = *(const float4*)&Bs[k][tn];
            float a[4] = {av.x, av.y, av.z, av.w};
            float b[4] = {bv.x, bv.y, bv.z, bv.w};
#pragma unroll
            for (int i = 0; i < 4; i++)
#pragma unroll
                for (int j = 0; j < 4; j++) acc[i][j] += a[i] * b[j];
        }
        __syncthreads();
    }
#pragma unroll
    for (int i = 0; i < 4; i++) {
        float4 o;
        o.x = acc[i][0] + (bias ? bias[n0 + tn + 0] : 0.f);
        o.y = acc[i][1] + (bias ? bias[n0 + tn + 1] : 0.f);
        o.z = acc[i][2] + (bias ? bias[n0 + tn + 2] : 0.f);
        o.w = acc[i][3] + (bias ? bias[n0 + tn + 3] : 0.f);
        *(float4*)&C[(size_t)(m0 + tm + i) * N + n0 + tn] = o;
    }
}

template <int BT>
__global__ __launch_bounds__(256) void gemm_k(
    const float* __restrict__ A, const float* __restrict__ B,
    const float* __restrict__ bias, float* __restrict__ C,
    int M, int N, int K)
{
    gemm_body<BT>(A, B, bias, C, M, N, K);
}

template <int BT>
__global__ __launch_bounds__(256) void gemm2_k(
    const float* __restrict__ A,
    const float* __restrict__ B0, const float* __restrict__ B1,
    const float* __restrict__ bias0, const float* __restrict__ bias1,
    float* __restrict__ C0, float* __restrict__ C1,
    int M, int N, int K)
{
    if (blockIdx.z == 0) gemm_body<BT>(A, B0, bias0, C0, M, N, K);
    else                 gemm_body<BT>(A, B1, bias1, C1, M, N, K);
}

// gi GEMM with fused concat: A = [v | c] (virtual [512,1024]), B^T layout.
__global__ __launch_bounds__(256) void gemm_gi_k(
    const float* __restrict__ v, const float* __restrict__ cc_,
    const float* __restrict__ B0, const float* __restrict__ B1,
    const float* __restrict__ bias0, const float* __restrict__ bias1,
    float* __restrict__ C0, float* __restrict__ C1)
{
    const float* B    = blockIdx.z ? B1 : B0;
    const float* bias = blockIdx.z ? bias1 : bias0;
    float* C          = blockIdx.z ? C1 : C0;
    const int N = 1536, K = 1024;

    __shared__ float As[16][68];
    __shared__ float Bs[16][68];
    int tid = threadIdx.x;
    int m0 = blockIdx.y * 64, n0 = blockIdx.x * 64;
    int tm = (tid & 15) * 4;
    int tn = (tid >> 4) * 4;
    float acc[4][4] = {};

    for (int k0 = 0; k0 < K; k0 += 16) {
        const float* Asrc = (k0 < 512) ? v : cc_;
        int koff = (k0 < 512) ? k0 : (k0 - 512);
        {
            int c = tid & 15, r0 = tid >> 4;
#pragma unroll
            for (int q = 0; q < 4; q++) {
                int r = r0 + q * 16;
                As[c][r] = Asrc[(size_t)(m0 + r) * 512 + koff + c];
            }
        }
        {
            int c = tid & 15, r0 = tid >> 4;
#pragma unroll
            for (int q = 0; q < 4; q++) {
                int n = r0 + q * 16;
                Bs[c][n] = B[(size_t)(n0 + n) * K + k0 + c];
            }
        }
        __syncthreads();
#pragma unroll
        for (int k = 0; k < 16; k++) {
            float4 av = *(const float4*)&As[k][tm];
            float4 bv = *(const float4*)&Bs[k][tn];
            float a[4] = {av.x, av.y, av.z, av.w};
            float b[4] = {bv.x, bv.y, bv.z, bv.w};
#pragma unroll
            for (int i = 0; i < 4; i++)
#pragma unroll
                for (int j = 0; j < 4; j++) acc[i][j] += a[i] * b[j];
        }
        __syncthreads();
    }
#pragma unroll
    for (int i = 0; i < 4; i++) {
        float4 o;
        o.x = acc[i][0] + bias[n0 + tn + 0];
        o.y = acc[i][1] + bias[n0 + tn + 1];
        o.z = acc[i][2] + bias[n0 + tn + 2];
        o.w = acc[i][3] + bias[n0 + tn + 3];
        *(float4*)&C[(size_t)(m0 + tm + i) * N + n0 + tn] = o;
    }
}

// ---------------- attention scores ----------------
__global__ __launch_bounds__(256) void attn_e_k(
    const float* __restrict__ u, const float* __restrict__ w,
    const float* __restrict__ v, float* __restrict__ e)
{
    __shared__ float wS[16][68];
    __shared__ float uS[32][68];
    __shared__ float vS[32][68];
    int tid = threadIdx.x;
    int t0 = blockIdx.y * 16, j0 = blockIdx.x * 32;
    int tt = tid >> 5, jj = tid & 31;
    float acc0 = 0.f, acc1 = 0.f;

    for (int d0 = 0; d0 < DD; d0 += 64) {
        {
            int c = tid & 63, r0 = tid >> 6;
#pragma unroll
            for (int q = 0; q < 4; q++)
                wS[r0 + q * 4][c] = w[(size_t)(t0 + r0 + q * 4) * DD + d0 + c];
#pragma unroll
            for (int q = 0; q < 8; q++) {
                int r = r0 + q * 4;
                uS[r][c] = u[(size_t)(j0 + r) * DD + d0 + c];
                vS[r][c] = v[(size_t)(j0 + r) * DD + d0 + c];
            }
        }
        __syncthreads();
#pragma unroll
        for (int c4 = 0; c4 < 16; c4++) {
            float4 uv = *(const float4*)&uS[jj][c4 * 4];
            float4 vv = *(const float4*)&vS[jj][c4 * 4];
            float4 w0 = *(const float4*)&wS[tt][c4 * 4];
            float4 w1 = *(const float4*)&wS[tt + 8][c4 * 4];
            acc0 += tanhf_fast(uv.x + w0.x) * vv.x;
            acc0 += tanhf_fast(uv.y + w0.y) * vv.y;
            acc0 += tanhf_fast(uv.z + w0.z) * vv.z;
            acc0 += tanhf_fast(uv.w + w0.w) * vv.w;
            acc1 += tanhf_fast(uv.x + w1.x) * vv.x;
            acc1 += tanhf_fast(uv.y + w1.y) * vv.y;
            acc1 += tanhf_fast(uv.z + w1.z) * vv.z;
            acc1 += tanhf_fast(uv.w + w1.w) * vv.w;
        }
        __syncthreads();
    }
    e[(size_t)(t0 + tt) * L + j0 + jj] = acc0;
    e[(size_t)(t0 + tt + 8) * L + j0 + jj] = acc1;
}

// ---------------- row softmax (in place) ----------------
__global__ __launch_bounds__(256) void softmax_k(float* __restrict__ e) {
    int t = blockIdx.x;
    float* row = e + (size_t)t * L;
    int tid = threadIdx.x;
    float v0 = row[tid], v1 = row[tid + 256];
    float m = fmaxf(v0, v1);
#pragma unroll
    for (int off = 32; off > 0; off >>= 1) m = fmaxf(m, __shfl_xor(m, off));
    __shared__ float red[4];
    __shared__ float red2[4];
    int wid = tid >> 6, lane = tid & 63;
    if (lane == 0) red[wid] = m;
    __syncthreads();
    m = fmaxf(fmaxf(red[0], red[1]), fmaxf(red[2], red[3]));
    float e0 = __expf(v0 - m), e1 = __expf(v1 - m);
    float s = e0 + e1;
#pragma unroll
    for (int off = 32; off > 0; off >>= 1) s += __shfl_xor(s, off);
    if (lane == 0) red2[wid] = s;
    __syncthreads();
    s = red2[0] + red2[1] + red2[2] + red2[3];
    float inv = __fdividef(1.f, s);
    row[tid] = e0 * inv;
    row[tid + 256] = e1 * inv;
}

// ---------------- GRU scan (round-6 structure + clean poll drains) --------
// 128 blocks x 256 threads. blocks [0,64): forward, [64,128): backward.
// Each block owns 8 h-indices (24 whh rows in registers, interleaved column
// layout => bank-conflict-free LDS matvec). h exchange via SELF-VALIDATING
// u32 words (24-bit fixed point scale 2^22 + 8-bit step tag); each thread
// polls its 2 words (tid, tid+256) with sticky 4B relaxed atomic loads.
// NEW vs r6: the poll's implicit vmcnt(0) drain is kept free of HBM ops —
// (1) gi prefetch for step s+1 issues at the TOP of step s (lands during
// matvec), (2) the HBM out-store moves AFTER poll detection. Only the 32B
// tagged L3 store is outstanding when polling starts.
// Parity ping-pong + skew<=1 step => tags never alias; 0xAA ws-poison can't
// match tags 1/2 of the first polls => no memset needed.
__global__ __launch_bounds__(256) void gru_scan_k(
    const float* __restrict__ whh_f, const float* __restrict__ bhh_f,
    const float* __restrict__ whh_b, const float* __restrict__ bhh_b,
    const float* __restrict__ gi_f, const float* __restrict__ gi_b,
    float* __restrict__ out,
    unsigned* __restrict__ hstage)   // [2 dirs][2 parity][512] encoded u32
{
    int blk = blockIdx.x;
    int dir = blk >> 6;          // 0 fwd, 1 bwd
    int bi = blk & 63;
    int hbase = bi * 8;
    const float* whh = dir ? whh_b : whh_f;
    const float* bhh = dir ? bhh_b : bhh_f;
    const float* gi  = dir ? gi_b : gi_f;
    float* outBase = out + dir * HH;       // row stride 1024
    unsigned* stage = hstage + dir * 1024;

    __shared__ float hS[HH];
    __shared__ float ghS[24];

    int tid = threadIdx.x;
    int rr = tid >> 3, c8 = tid & 7;
    bool active = rr < 24;

    // whh weights into registers, interleaved columns: thread c8 owns float4
    // slots {q*8 + c8 : q in [0,16)} of its row (conflict-free LDS reads).
    float4 wreg[16];
    float bhv = 0.f;
    if (active) {
        int g = rr >> 3, i = rr & 7;
        const float4* wrow = (const float4*)(whh + (size_t)(g * HH + hbase + i) * HH);
#pragma unroll
        for (int q = 0; q < 16; q++) wreg[q] = wrow[q * 8 + c8];
        if (c8 == 0) bhv = bhh[g * HH + hbase + i];
    }
    for (int j = tid; j < HH; j += 256) hS[j] = 0.f;

    // prefetch gi for step 0
    float ir = 0.f, iz = 0.f, inn = 0.f;
    float ir2 = 0.f, iz2 = 0.f, inn2 = 0.f;
    if (tid < 8) {
        int t0 = dir ? (L - 1) : 0;
        const float* git = gi + (size_t)t0 * (3 * HH);
        ir  = git[hbase + tid];
        iz  = git[HH + hbase + tid];
        inn = git[2 * HH + hbase + tid];
    }
    __syncthreads();

    const float ENC = 4194304.0f;            // 2^22
    const float DEC = 1.0f / 4194304.0f;

    for (int s = 0; s < L; s++) {
        int t = dir ? (L - 1 - s) : s;

        // issue NEXT step's gi HBM loads now; they land during the matvec so
        // the poll's vmcnt(0) drain never waits on them
        if (tid < 8 && s < L - 1) {
            int tn = dir ? (L - 2 - s) : (s + 1);
            const float* git = gi + (size_t)tn * (3 * HH);
            ir2  = git[hbase + tid];
            iz2  = git[HH + hbase + tid];
            inn2 = git[2 * HH + hbase + tid];
        }

        float acc = 0.f;
        if (active) {
            const float4* h4 = (const float4*)hS;
#pragma unroll
            for (int q = 0; q < 16; q++) {
                float4 hv = h4[q * 8 + c8];   // lanes 16B apart: all 32 banks
                acc += wreg[q].x * hv.x + wreg[q].y * hv.y
                     + wreg[q].z * hv.z + wreg[q].w * hv.w;
            }
            acc += __shfl_xor(acc, 1);
            acc += __shfl_xor(acc, 2);
            acc += __shfl_xor(acc, 4);
            if (c8 == 0) ghS[rr] = acc + bhv;
        }
        __syncthreads();

        float hnew = 0.f;
        if (tid < 8) {
            int i = tid, hg = hbase + i;
            float r = sigmoidf_fast(ir + ghS[i]);
            float z = sigmoidf_fast(iz + ghS[8 + i]);
            float n = tanhf_fast(inn + r * ghS[16 + i]);
            hnew = (1.f - z) * n + z * hS[hg];
            // tagged L3 store: the ONLY vmem op outstanding at poll time
            unsigned enc = ((unsigned)__float2int_rn(hnew * ENC) & 0x00FFFFFFu)
                         | ((unsigned)((s + 1) & 0xFF) << 24);
            __hip_atomic_store(stage + (s & 1) * 512 + hg, enc,
                               __ATOMIC_RELAXED, __HIP_MEMORY_SCOPE_AGENT);
        }

        if (s == L - 1) {
            if (tid < 8) outBase[(size_t)t * 1024 + hbase + tid] = hnew;
            break;
        }

        // poll this thread's two words (data IS the flag)
        {
            unsigned tag = (unsigned)((s + 1) & 0xFF);
            const unsigned* src = stage + (s & 1) * 512;
            unsigned e0 = 0, e1 = 0;
            bool g0 = false, g1 = false;
            do {
                if (!g0) {
                    e0 = __hip_atomic_load(src + tid, __ATOMIC_RELAXED,
                                           __HIP_MEMORY_SCOPE_AGENT);
                    g0 = ((e0 >> 24) == tag);
                }
                if (!g1) {
                    e1 = __hip_atomic_load(src + tid + 256, __ATOMIC_RELAXED,
                                           __HIP_MEMORY_SCOPE_AGENT);
                    g1 = ((e1 >> 24) == tag);
                }
            } while (!(g0 && g1));

            // deferred HBM out-store + gi double-buffer swap (off poll path)
            if (tid < 8) {
                outBase[(size_t)t * 1024 + hbase + tid] = hnew;
                ir = ir2; iz = iz2; inn = inn2;
            }

            hS[tid]       = (float)(((int)(e0 << 8)) >> 8) * DEC;
            hS[tid + 256] = (float)(((int)(e1 << 8)) >> 8) * DEC;
        }
        __syncthreads();
    }
}

extern "C" void kernel_launch(void* const* d_in, const int* in_sizes, int n_in,
                              void* d_out, int out_size, void* d_ws, size_t ws_size,
                              hipStream_t stream) {
    const float* v     = (const float*)d_in[0];
    const float* w1    = (const float*)d_in[1];
    const float* b1    = (const float*)d_in[2];
    const float* w2    = (const float*)d_in[3];
    const float* b2    = (const float*)d_in[4];
    const float* wih_f = (const float*)d_in[5];
    const float* whh_f = (const float*)d_in[6];
    const float* bih_f = (const float*)d_in[7];
    const float* bhh_f = (const float*)d_in[8];
    const float* wih_b = (const float*)d_in[9];
    const float* whh_b = (const float*)d_in[10];
    const float* bih_b = (const float*)d_in[11];
    const float* bhh_b = (const float*)d_in[12];
    float* out = (float*)d_out;   // f32 [512, 1024]

    float* ws = (float*)d_ws;
    float* u   = ws;                 // 512*512
    float* w_  = ws + 262144;        // 512*512
    float* e   = ws + 524288;        // 512*512 (becomes a after softmax)
    float* c   = ws + 786432;        // 512*512
    float* gif = ws + 1572864;       // 512*1536
    float* gib = ws + 2359296;       // 512*1536
    unsigned* hstage = (unsigned*)(ws + 3145728);  // 2*2*512 u32 (no init needed)

    // u = v @ w1^T + b1 ; w = v @ w2^T + b2  (one launch, z selects)
    gemm2_k<1><<<dim3(8, 8, 2), 256, 0, stream>>>(v, w1, w2, b1, b2, u, w_,
                                                  512, 512, 512);

    // e[t,j] = sum_d tanh(u[j,d]+w[t,d]) v[j,d]
    attn_e_k<<<dim3(16, 32), 256, 0, stream>>>(u, w_, v, e);
    softmax_k<<<512, 256, 0, stream>>>(e);

    // c = a @ v
    gemm_k<0><<<dim3(8, 8), 256, 0, stream>>>(e, v, nullptr, c, 512, 512, 512);

    // gi = [v|c] @ wih^T + bih, both directions, concat fused into A-load
    gemm_gi_k<<<dim3(24, 8, 2), 256, 0, stream>>>(v, c, wih_f, wih_b,
                                                  bih_f, bih_b, gif, gib);

    gru_scan_k<<<128, 256, 0, stream>>>(whh_f, bhh_f, whh_b, bhh_b,
                                        gif, gib, out, hstage);
}

// Round 12
// 1323.429 us; speedup vs baseline: 1.6364x; 1.0131x over previous
//
#include <hip/hip_runtime.h>
#include <hip/hip_bf16.h>

// Problem: L=D=H=512 self-matching additive attention + bidirectional GRU.
// Inputs f32 (13 tensors), output f32 [512, 1024] = [hf | hb].

#define L 512
#define DD 512
#define HH 512

__device__ __forceinline__ float tanhf_fast(float x) {
    float ex = __expf(2.f * x);
    return 1.f - __fdividef(2.f, ex + 1.f);
}

__device__ __forceinline__ float sigmoidf_fast(float x) {
    return __fdividef(1.f, 1.f + __expf(-x));
}

// ---------------- GEMM body: C[M,N] = A[M,K] * op(B) + bias ----------------
// KC=32, float4 global staging. BT=1: B is [N,K] -> C = A@B^T ; BT=0: B [K,N].
template <int BT>
__device__ __forceinline__ void gemm_body(
    const float* __restrict__ A, const float* __restrict__ B,
    const float* __restrict__ bias, float* __restrict__ C,
    int M, int N, int K)
{
    __shared__ float As[32][68];
    __shared__ float Bs[32][68];
    int tid = threadIdx.x;
    int m0 = blockIdx.y * 64, n0 = blockIdx.x * 64;
    int tm = (tid & 15) * 4;
    int tn = (tid >> 4) * 4;
    float acc[4][4] = {};

    for (int k0 = 0; k0 < K; k0 += 32) {
        // A tile 64m x 32k: float4 loads, transposed scalar stores
        {
            int c8 = tid & 7, r0 = tid >> 3;   // c8: k-quad, r0: 0..31
#pragma unroll
            for (int half = 0; half < 2; half++) {
                int r = r0 + half * 32;
                float4 a4 = *(const float4*)&A[(size_t)(m0 + r) * K + k0 + c8 * 4];
                As[c8 * 4 + 0][r] = a4.x;
                As[c8 * 4 + 1][r] = a4.y;
                As[c8 * 4 + 2][r] = a4.z;
                As[c8 * 4 + 3][r] = a4.w;
            }
        }
        if (BT) {
            int c8 = tid & 7, r0 = tid >> 3;
#pragma unroll
            for (int half = 0; half < 2; half++) {
                int n = r0 + half * 32;
                float4 b4 = *(const float4*)&B[(size_t)(n0 + n) * K + k0 + c8 * 4];
                Bs[c8 * 4 + 0][n] = b4.x;
                Bs[c8 * 4 + 1][n] = b4.y;
                Bs[c8 * 4 + 2][n] = b4.z;
                Bs[c8 * 4 + 3][n] = b4.w;
            }
        } else {
            int c16 = tid & 15, r0 = tid >> 4;  // c16: n-quad, r0: 0..15
#pragma unroll
            for (int half = 0; half < 2; half++) {
                int k = r0 + half * 16;
                float4 b4 = *(const float4*)&B[(size_t)(k0 + k) * N + n0 + c16 * 4];
                *(float4*)&Bs[k][c16 * 4] = b4;
            }
        }
        __syncthreads();
#pragma unroll
        for (int k = 0; k < 32; k++) {
            float4 av = *(const float4*)&As[k][tm];
            float4 bv = *(const float4*)&Bs[k][tn];
            float a[4] = {av.x, av.y, av.z, av.w};
            float b[4] = {bv.x, bv.y, bv.z, bv.w};
#pragma unroll
            for (int i = 0; i < 4; i++)
#pragma unroll
                for (int j = 0; j < 4; j++) acc[i][j] += a[i] * b[j];
        }
        __syncthreads();
    }
#pragma unroll
    for (int i = 0; i < 4; i++) {
        float4 o;
        o.x = acc[i][0] + (bias ? bias[n0 + tn + 0] : 0.f);
        o.y = acc[i][1] + (bias ? bias[n0 + tn + 1] : 0.f);
        o.z = acc[i][2] + (bias ? bias[n0 + tn + 2] : 0.f);
        o.w = acc[i][3] + (bias ? bias[n0 + tn + 3] : 0.f);
        *(float4*)&C[(size_t)(m0 + tm + i) * N + n0 + tn] = o;
    }
}

template <int BT>
__global__ __launch_bounds__(256) void gemm_k(
    const float* __restrict__ A, const float* __restrict__ B,
    const float* __restrict__ bias, float* __restrict__ C,
    int M, int N, int K)
{
    gemm_body<BT>(A, B, bias, C, M, N, K);
}

template <int BT>
__global__ __launch_bounds__(256) void gemm2_k(
    const float* __restrict__ A,
    const float* __restrict__ B0, const float* __restrict__ B1,
    const float* __restrict__ bias0, const float* __restrict__ bias1,
    float* __restrict__ C0, float* __restrict__ C1,
    int M, int N, int K)
{
    if (blockIdx.z == 0) gemm_body<BT>(A, B0, bias0, C0, M, N, K);
    else                 gemm_body<BT>(A, B1, bias1, C1, M, N, K);
}

// gi GEMM with fused concat: A = [v | c] (virtual [512,1024]), B^T layout.
// KC=32 tiles never straddle the 512 boundary.
__global__ __launch_bounds__(256) void gemm_gi_k(
    const float* __restrict__ v, const float* __restrict__ cc_,
    const float* __restrict__ B0, const float* __restrict__ B1,
    const float* __restrict__ bias0, const float* __restrict__ bias1,
    float* __restrict__ C0, float* __restrict__ C1)
{
    const float* B    = blockIdx.z ? B1 : B0;
    const float* bias = blockIdx.z ? bias1 : bias0;
    float* C          = blockIdx.z ? C1 : C0;
    const int N = 1536, K = 1024;

    __shared__ float As[32][68];
    __shared__ float Bs[32][68];
    int tid = threadIdx.x;
    int m0 = blockIdx.y * 64, n0 = blockIdx.x * 64;
    int tm = (tid & 15) * 4;
    int tn = (tid >> 4) * 4;
    float acc[4][4] = {};

    for (int k0 = 0; k0 < K; k0 += 32) {
        const float* Asrc = (k0 < 512) ? v : cc_;
        int koff = (k0 < 512) ? k0 : (k0 - 512);
        {
            int c8 = tid & 7, r0 = tid >> 3;
#pragma unroll
            for (int half = 0; half < 2; half++) {
                int r = r0 + half * 32;
                float4 a4 = *(const float4*)&Asrc[(size_t)(m0 + r) * 512 + koff + c8 * 4];
                As[c8 * 4 + 0][r] = a4.x;
                As[c8 * 4 + 1][r] = a4.y;
                As[c8 * 4 + 2][r] = a4.z;
                As[c8 * 4 + 3][r] = a4.w;
            }
        }
        {
            int c8 = tid & 7, r0 = tid >> 3;
#pragma unroll
            for (int half = 0; half < 2; half++) {
                int n = r0 + half * 32;
                float4 b4 = *(const float4*)&B[(size_t)(n0 + n) * K + k0 + c8 * 4];
                Bs[c8 * 4 + 0][n] = b4.x;
                Bs[c8 * 4 + 1][n] = b4.y;
                Bs[c8 * 4 + 2][n] = b4.z;
                Bs[c8 * 4 + 3][n] = b4.w;
            }
        }
        __syncthreads();
#pragma unroll
        for (int k = 0; k < 32; k++) {
            float4 av = *(const float4*)&As[k][tm];
            float4 bv = *(const float4*)&Bs[k][tn];
            float a[4] = {av.x, av.y, av.z, av.w};
            float b[4] = {bv.x, bv.y, bv.z, bv.w};
#pragma unroll
            for (int i = 0; i < 4; i++)
#pragma unroll
                for (int j = 0; j < 4; j++) acc[i][j] += a[i] * b[j];
        }
        __syncthreads();
    }
#pragma unroll
    for (int i = 0; i < 4; i++) {
        float4 o;
        o.x = acc[i][0] + bias[n0 + tn + 0];
        o.y = acc[i][1] + bias[n0 + tn + 1];
        o.z = acc[i][2] + bias[n0 + tn + 2];
        o.w = acc[i][3] + bias[n0 + tn + 3];
        *(float4*)&C[(size_t)(m0 + tm + i) * N + n0 + tn] = o;
    }
}

// ---------------- attention scores ----------------
__global__ __launch_bounds__(256) void attn_e_k(
    const float* __restrict__ u, const float* __restrict__ w,
    const float* __restrict__ v, float* __restrict__ e)
{
    __shared__ float wS[16][68];
    __shared__ float uS[32][68];
    __shared__ float vS[32][68];
    int tid = threadIdx.x;
    int t0 = blockIdx.y * 16, j0 = blockIdx.x * 32;
    int tt = tid >> 5, jj = tid & 31;
    float acc0 = 0.f, acc1 = 0.f;

    for (int d0 = 0; d0 < DD; d0 += 64) {
        {
            int c = tid & 63, r0 = tid >> 6;
#pragma unroll
            for (int q = 0; q < 4; q++)
                wS[r0 + q * 4][c] = w[(size_t)(t0 + r0 + q * 4) * DD + d0 + c];
#pragma unroll
            for (int q = 0; q < 8; q++) {
                int r = r0 + q * 4;
                uS[r][c] = u[(size_t)(j0 + r) * DD + d0 + c];
                vS[r][c] = v[(size_t)(j0 + r) * DD + d0 + c];
            }
        }
        __syncthreads();
#pragma unroll
        for (int c4 = 0; c4 < 16; c4++) {
            float4 uv = *(const float4*)&uS[jj][c4 * 4];
            float4 vv = *(const float4*)&vS[jj][c4 * 4];
            float4 w0 = *(const float4*)&wS[tt][c4 * 4];
            float4 w1 = *(const float4*)&wS[tt + 8][c4 * 4];
            acc0 += tanhf_fast(uv.x + w0.x) * vv.x;
            acc0 += tanhf_fast(uv.y + w0.y) * vv.y;
            acc0 += tanhf_fast(uv.z + w0.z) * vv.z;
            acc0 += tanhf_fast(uv.w + w0.w) * vv.w;
            acc1 += tanhf_fast(uv.x + w1.x) * vv.x;
            acc1 += tanhf_fast(uv.y + w1.y) * vv.y;
            acc1 += tanhf_fast(uv.z + w1.z) * vv.z;
            acc1 += tanhf_fast(uv.w + w1.w) * vv.w;
        }
        __syncthreads();
    }
    e[(size_t)(t0 + tt) * L + j0 + jj] = acc0;
    e[(size_t)(t0 + tt + 8) * L + j0 + jj] = acc1;
}

// ---------------- row softmax (in place) ----------------
__global__ __launch_bounds__(256) void softmax_k(float* __restrict__ e) {
    int t = blockIdx.x;
    float* row = e + (size_t)t * L;
    int tid = threadIdx.x;
    float v0 = row[tid], v1 = row[tid + 256];
    float m = fmaxf(v0, v1);
#pragma unroll
    for (int off = 32; off > 0; off >>= 1) m = fmaxf(m, __shfl_xor(m, off));
    __shared__ float red[4];
    __shared__ float red2[4];
    int wid = tid >> 6, lane = tid & 63;
    if (lane == 0) red[wid] = m;
    __syncthreads();
    m = fmaxf(fmaxf(red[0], red[1]), fmaxf(red[2], red[3]));
    float e0 = __expf(v0 - m), e1 = __expf(v1 - m);
    float s = e0 + e1;
#pragma unroll
    for (int off = 32; off > 0; off >>= 1) s += __shfl_xor(s, off);
    if (lane == 0) red2[wid] = s;
    __syncthreads();
    s = red2[0] + red2[1] + red2[2] + red2[3];
    float inv = __fdividef(1.f, s);
    row[tid] = e0 * inv;
    row[tid + 256] = e1 * inv;
}

// ---------------- GRU scan: EXACT round-6 kernel (946 us proven) ----------
// 128 blocks x 256 threads. blocks [0,64): forward, [64,128): backward.
// Each block owns 8 h-indices (24 whh rows in registers, interleaved column
// layout => bank-conflict-free LDS matvec). h exchange via SELF-VALIDATING
// words (24-bit fixed point scale 2^22 + 8-bit step tag per u32). Order
// matters (measured r6 vs r8/r10): out-store BEFORE tagged store; gi
// prefetch between store and poll; NOTHING between poll detection and the
// hS write. Ping-pong parity; skew <= 1 step => tags never alias; 0xAA
// ws-poison can't match tags 1/2 => no memset needed.
__global__ __launch_bounds__(256) void gru_scan_k(
    const float* __restrict__ whh_f, const float* __restrict__ bhh_f,
    const float* __restrict__ whh_b, const float* __restrict__ bhh_b,
    const float* __restrict__ gi_f, const float* __restrict__ gi_b,
    float* __restrict__ out,
    unsigned* __restrict__ hstage)   // [2 dirs][2 parity][512] encoded u32
{
    int blk = blockIdx.x;
    int dir = blk >> 6;          // 0 fwd, 1 bwd
    int bi = blk & 63;
    int hbase = bi * 8;
    const float* whh = dir ? whh_b : whh_f;
    const float* bhh = dir ? bhh_b : bhh_f;
    const float* gi  = dir ? gi_b : gi_f;
    float* outBase = out + dir * HH;       // row stride 1024
    unsigned* stage = hstage + dir * 1024;

    __shared__ float hS[HH];
    __shared__ float ghS[24];

    int tid = threadIdx.x;
    int rr = tid >> 3, c8 = tid & 7;
    bool active = rr < 24;

    float4 wreg[16];
    float bhv = 0.f;
    if (active) {
        int g = rr >> 3, i = rr & 7;
        const float4* wrow = (const float4*)(whh + (size_t)(g * HH + hbase + i) * HH);
#pragma unroll
        for (int q = 0; q < 16; q++) wreg[q] = wrow[q * 8 + c8];
        if (c8 == 0) bhv = bhh[g * HH + hbase + i];
    }
    for (int j = tid; j < HH; j += 256) hS[j] = 0.f;

    float ir = 0.f, iz = 0.f, inn = 0.f;
    if (tid < 8) {
        int t0 = dir ? (L - 1) : 0;
        const float* git = gi + (size_t)t0 * (3 * HH);
        ir  = git[hbase + tid];
        iz  = git[HH + hbase + tid];
        inn = git[2 * HH + hbase + tid];
    }
    __syncthreads();

    const float ENC = 4194304.0f;            // 2^22
    const float DEC = 1.0f / 4194304.0f;

    for (int s = 0; s < L; s++) {
        int t = dir ? (L - 1 - s) : s;

        float acc = 0.f;
        if (active) {
            const float4* h4 = (const float4*)hS;
#pragma unroll
            for (int q = 0; q < 16; q++) {
                float4 hv = h4[q * 8 + c8];   // lanes 16B apart: all 32 banks
                acc += wreg[q].x * hv.x + wreg[q].y * hv.y
                     + wreg[q].z * hv.z + wreg[q].w * hv.w;
            }
            acc += __shfl_xor(acc, 1);
            acc += __shfl_xor(acc, 2);
            acc += __shfl_xor(acc, 4);
            if (c8 == 0) ghS[rr] = acc + bhv;
        }
        __syncthreads();

        if (tid < 8) {
            int i = tid, hg = hbase + i;
            float r = sigmoidf_fast(ir + ghS[i]);
            float z = sigmoidf_fast(iz + ghS[8 + i]);
            float n = tanhf_fast(inn + r * ghS[16 + i]);
            float hnew = (1.f - z) * n + z * hS[hg];
            outBase[(size_t)t * 1024 + hg] = hnew;   // full-precision output
            unsigned enc = ((unsigned)__float2int_rn(hnew * ENC) & 0x00FFFFFFu)
                         | ((unsigned)((s + 1) & 0xFF) << 24);
            __hip_atomic_store(stage + (s & 1) * 512 + hg, enc,
                               __ATOMIC_RELAXED, __HIP_MEMORY_SCOPE_AGENT);
        }

        if (s == L - 1) break;

        // prefetch next step's gi while waiting on data
        if (tid < 8) {
            int tn = dir ? (L - 2 - s) : (s + 1);
            const float* git = gi + (size_t)tn * (3 * HH);
            ir  = git[hbase + tid];
            iz  = git[HH + hbase + tid];
            inn = git[2 * HH + hbase + tid];
        }

        // poll the two words this thread consumes (data IS the flag)
        {
            unsigned tag = (unsigned)((s + 1) & 0xFF);
            const unsigned* src = stage + (s & 1) * 512;
            unsigned e0 = 0, e1 = 0;
            bool g0 = false, g1 = false;
            do {
                if (!g0) {
                    e0 = __hip_atomic_load(src + tid, __ATOMIC_RELAXED,
                                           __HIP_MEMORY_SCOPE_AGENT);
                    g0 = ((e0 >> 24) == tag);
                }
                if (!g1) {
                    e1 = __hip_atomic_load(src + tid + 256, __ATOMIC_RELAXED,
                                           __HIP_MEMORY_SCOPE_AGENT);
                    g1 = ((e1 >> 24) == tag);
                }
            } while (!(g0 && g1));
            hS[tid]       = (float)(((int)(e0 << 8)) >> 8) * DEC;
            hS[tid + 256] = (float)(((int)(e1 << 8)) >> 8) * DEC;
        }
        __syncthreads();
    }
}

extern "C" void kernel_launch(void* const* d_in, const int* in_sizes, int n_in,
                              void* d_out, int out_size, void* d_ws, size_t ws_size,
                              hipStream_t stream) {
    const float* v     = (const float*)d_in[0];
    const float* w1    = (const float*)d_in[1];
    const float* b1    = (const float*)d_in[2];
    const float* w2    = (const float*)d_in[3];
    const float* b2    = (const float*)d_in[4];
    const float* wih_f = (const float*)d_in[5];
    const float* whh_f = (const float*)d_in[6];
    const float* bih_f = (const float*)d_in[7];
    const float* bhh_f = (const float*)d_in[8];
    const float* wih_b = (const float*)d_in[9];
    const float* whh_b = (const float*)d_in[10];
    const float* bih_b = (const float*)d_in[11];
    const float* bhh_b = (const float*)d_in[12];
    float* out = (float*)d_out;   // f32 [512, 1024]

    float* ws = (float*)d_ws;
    float* u   = ws;                 // 512*512
    float* w_  = ws + 262144;        // 512*512
    float* e   = ws + 524288;        // 512*512 (becomes a after softmax)
    float* c   = ws + 786432;        // 512*512
    float* gif = ws + 1572864;       // 512*1536
    float* gib = ws + 2359296;       // 512*1536
    unsigned* hstage = (unsigned*)(ws + 3145728);  // 2*2*512 u32 (no init needed)

    // u = v @ w1^T + b1 ; w = v @ w2^T + b2  (one launch, z selects)
    gemm2_k<1><<<dim3(8, 8, 2), 256, 0, stream>>>(v, w1, w2, b1, b2, u, w_,
                                                  512, 512, 512);

    // e[t,j] = sum_d tanh(u[j,d]+w[t,d]) v[j,d]
    attn_e_k<<<dim3(16, 32), 256, 0, stream>>>(u, w_, v, e);
    softmax_k<<<512, 256, 0, stream>>>(e);

    // c = a @ v
    gemm_k<0><<<dim3(8, 8), 256, 0, stream>>>(e, v, nullptr, c, 512, 512, 512);

    // gi = [v|c] @ wih^T + bih, both directions, concat fused into A-load
    gemm_gi_k<<<dim3(24, 8, 2), 256, 0, stream>>>(v, c, wih_f, wih_b,
                                                  bih_f, bih_b, gif, gib);

    gru_scan_k<<<128, 256, 0, stream>>>(whh_f, bhh_f, whh_b, bhh_b,
                                        gif, gib, out, hstage);
}

// Round 13
// 1298.229 us; speedup vs baseline: 1.6682x; 1.0194x over previous
//
#include <hip/hip_runtime.h>
#include <hip/hip_bf16.h>

// Problem: L=D=H=512 self-matching additive attention + bidirectional GRU.
// Inputs f32 (13 tensors), output f32 [512, 1024] = [hf | hb].

#define L 512
#define DD 512
#define HH 512

__device__ __forceinline__ float tanhf_fast(float x) {
    float ex = __expf(2.f * x);
    return 1.f - __fdividef(2.f, ex + 1.f);
}

__device__ __forceinline__ float sigmoidf_fast(float x) {
    return __fdividef(1.f, 1.f + __expf(-x));
}

// ---------------- GEMM body: C[M,N] = A[M,K] * op(B) + bias ----------------
// KC=32, float4 global staging. BT=1: B is [N,K] -> C = A@B^T ; BT=0: B [K,N].
template <int BT>
__device__ __forceinline__ void gemm_body(
    const float* __restrict__ A, const float* __restrict__ B,
    const float* __restrict__ bias, float* __restrict__ C,
    int M, int N, int K)
{
    __shared__ float As[32][68];
    __shared__ float Bs[32][68];
    int tid = threadIdx.x;
    int m0 = blockIdx.y * 64, n0 = blockIdx.x * 64;
    int tm = (tid & 15) * 4;
    int tn = (tid >> 4) * 4;
    float acc[4][4] = {};

    for (int k0 = 0; k0 < K; k0 += 32) {
        // A tile 64m x 32k: float4 loads, transposed scalar stores
        {
            int c8 = tid & 7, r0 = tid >> 3;   // c8: k-quad, r0: 0..31
#pragma unroll
            for (int half = 0; half < 2; half++) {
                int r = r0 + half * 32;
                float4 a4 = *(const float4*)&A[(size_t)(m0 + r) * K + k0 + c8 * 4];
                As[c8 * 4 + 0][r] = a4.x;
                As[c8 * 4 + 1][r] = a4.y;
                As[c8 * 4 + 2][r] = a4.z;
                As[c8 * 4 + 3][r] = a4.w;
            }
        }
        if (BT) {
            int c8 = tid & 7, r0 = tid >> 3;
#pragma unroll
            for (int half = 0; half < 2; half++) {
                int n = r0 + half * 32;
                float4 b4 = *(const float4*)&B[(size_t)(n0 + n) * K + k0 + c8 * 4];
                Bs[c8 * 4 + 0][n] = b4.x;
                Bs[c8 * 4 + 1][n] = b4.y;
                Bs[c8 * 4 + 2][n] = b4.z;
                Bs[c8 * 4 + 3][n] = b4.w;
            }
        } else {
            int c16 = tid & 15, r0 = tid >> 4;  // c16: n-quad, r0: 0..15
#pragma unroll
            for (int half = 0; half < 2; half++) {
                int k = r0 + half * 16;
                float4 b4 = *(const float4*)&B[(size_t)(k0 + k) * N + n0 + c16 * 4];
                *(float4*)&Bs[k][c16 * 4] = b4;
            }
        }
        __syncthreads();
#pragma unroll
        for (int k = 0; k < 32; k++) {
            float4 av = *(const float4*)&As[k][tm];
            float4 bv = *(const float4*)&Bs[k][tn];
            float a[4] = {av.x, av.y, av.z, av.w};
            float b[4] = {bv.x, bv.y, bv.z, bv.w};
#pragma unroll
            for (int i = 0; i < 4; i++)
#pragma unroll
                for (int j = 0; j < 4; j++) acc[i][j] += a[i] * b[j];
        }
        __syncthreads();
    }
#pragma unroll
    for (int i = 0; i < 4; i++) {
        float4 o;
        o.x = acc[i][0] + (bias ? bias[n0 + tn + 0] : 0.f);
        o.y = acc[i][1] + (bias ? bias[n0 + tn + 1] : 0.f);
        o.z = acc[i][2] + (bias ? bias[n0 + tn + 2] : 0.f);
        o.w = acc[i][3] + (bias ? bias[n0 + tn + 3] : 0.f);
        *(float4*)&C[(size_t)(m0 + tm + i) * N + n0 + tn] = o;
    }
}

template <int BT>
__global__ __launch_bounds__(256) void gemm_k(
    const float* __restrict__ A, const float* __restrict__ B,
    const float* __restrict__ bias, float* __restrict__ C,
    int M, int N, int K)
{
    gemm_body<BT>(A, B, bias, C, M, N, K);
}

template <int BT>
__global__ __launch_bounds__(256) void gemm2_k(
    const float* __restrict__ A,
    const float* __restrict__ B0, const float* __restrict__ B1,
    const float* __restrict__ bias0, const float* __restrict__ bias1,
    float* __restrict__ C0, float* __restrict__ C1,
    int M, int N, int K)
{
    if (blockIdx.z == 0) gemm_body<BT>(A, B0, bias0, C0, M, N, K);
    else                 gemm_body<BT>(A, B1, bias1, C1, M, N, K);
}

// gi GEMM with fused concat: A = [v | c] (virtual [512,1024]), B^T layout.
// KC=32 tiles never straddle the 512 boundary.
__global__ __launch_bounds__(256) void gemm_gi_k(
    const float* __restrict__ v, const float* __restrict__ cc_,
    const float* __restrict__ B0, const float* __restrict__ B1,
    const float* __restrict__ bias0, const float* __restrict__ bias1,
    float* __restrict__ C0, float* __restrict__ C1)
{
    const float* B    = blockIdx.z ? B1 : B0;
    const float* bias = blockIdx.z ? bias1 : bias0;
    float* C          = blockIdx.z ? C1 : C0;
    const int N = 1536, K = 1024;

    __shared__ float As[32][68];
    __shared__ float Bs[32][68];
    int tid = threadIdx.x;
    int m0 = blockIdx.y * 64, n0 = blockIdx.x * 64;
    int tm = (tid & 15) * 4;
    int tn = (tid >> 4) * 4;
    float acc[4][4] = {};

    for (int k0 = 0; k0 < K; k0 += 32) {
        const float* Asrc = (k0 < 512) ? v : cc_;
        int koff = (k0 < 512) ? k0 : (k0 - 512);
        {
            int c8 = tid & 7, r0 = tid >> 3;
#pragma unroll
            for (int half = 0; half < 2; half++) {
                int r = r0 + half * 32;
                float4 a4 = *(const float4*)&Asrc[(size_t)(m0 + r) * 512 + koff + c8 * 4];
                As[c8 * 4 + 0][r] = a4.x;
                As[c8 * 4 + 1][r] = a4.y;
                As[c8 * 4 + 2][r] = a4.z;
                As[c8 * 4 + 3][r] = a4.w;
            }
        }
        {
            int c8 = tid & 7, r0 = tid >> 3;
#pragma unroll
            for (int half = 0; half < 2; half++) {
                int n = r0 + half * 32;
                float4 b4 = *(const float4*)&B[(size_t)(n0 + n) * K + k0 + c8 * 4];
                Bs[c8 * 4 + 0][n] = b4.x;
                Bs[c8 * 4 + 1][n] = b4.y;
                Bs[c8 * 4 + 2][n] = b4.z;
                Bs[c8 * 4 + 3][n] = b4.w;
            }
        }
        __syncthreads();
#pragma unroll
        for (int k = 0; k < 32; k++) {
            float4 av = *(const float4*)&As[k][tm];
            float4 bv = *(const float4*)&Bs[k][tn];
            float a[4] = {av.x, av.y, av.z, av.w};
            float b[4] = {bv.x, bv.y, bv.z, bv.w};
#pragma unroll
            for (int i = 0; i < 4; i++)
#pragma unroll
                for (int j = 0; j < 4; j++) acc[i][j] += a[i] * b[j];
        }
        __syncthreads();
    }
#pragma unroll
    for (int i = 0; i < 4; i++) {
        float4 o;
        o.x = acc[i][0] + bias[n0 + tn + 0];
        o.y = acc[i][1] + bias[n0 + tn + 1];
        o.z = acc[i][2] + bias[n0 + tn + 2];
        o.w = acc[i][3] + bias[n0 + tn + 3];
        *(float4*)&C[(size_t)(m0 + tm + i) * N + n0 + tn] = o;
    }
}

// ---------------- attention scores ----------------
__global__ __launch_bounds__(256) void attn_e_k(
    const float* __restrict__ u, const float* __restrict__ w,
    const float* __restrict__ v, float* __restrict__ e)
{
    __shared__ float wS[16][68];
    __shared__ float uS[32][68];
    __shared__ float vS[32][68];
    int tid = threadIdx.x;
    int t0 = blockIdx.y * 16, j0 = blockIdx.x * 32;
    int tt = tid >> 5, jj = tid & 31;
    float acc0 = 0.f, acc1 = 0.f;

    for (int d0 = 0; d0 < DD; d0 += 64) {
        {
            int c = tid & 63, r0 = tid >> 6;
#pragma unroll
            for (int q = 0; q < 4; q++)
                wS[r0 + q * 4][c] = w[(size_t)(t0 + r0 + q * 4) * DD + d0 + c];
#pragma unroll
            for (int q = 0; q < 8; q++) {
                int r = r0 + q * 4;
                uS[r][c] = u[(size_t)(j0 + r) * DD + d0 + c];
                vS[r][c] = v[(size_t)(j0 + r) * DD + d0 + c];
            }
        }
        __syncthreads();
#pragma unroll
        for (int c4 = 0; c4 < 16; c4++) {
            float4 uv = *(const float4*)&uS[jj][c4 * 4];
            float4 vv = *(const float4*)&vS[jj][c4 * 4];
            float4 w0 = *(const float4*)&wS[tt][c4 * 4];
            float4 w1 = *(const float4*)&wS[tt + 8][c4 * 4];
            acc0 += tanhf_fast(uv.x + w0.x) * vv.x;
            acc0 += tanhf_fast(uv.y + w0.y) * vv.y;
            acc0 += tanhf_fast(uv.z + w0.z) * vv.z;
            acc0 += tanhf_fast(uv.w + w0.w) * vv.w;
            acc1 += tanhf_fast(uv.x + w1.x) * vv.x;
            acc1 += tanhf_fast(uv.y + w1.y) * vv.y;
            acc1 += tanhf_fast(uv.z + w1.z) * vv.z;
            acc1 += tanhf_fast(uv.w + w1.w) * vv.w;
        }
        __syncthreads();
    }
    e[(size_t)(t0 + tt) * L + j0 + jj] = acc0;
    e[(size_t)(t0 + tt + 8) * L + j0 + jj] = acc1;
}

// ---------------- row softmax (in place) ----------------
__global__ __launch_bounds__(256) void softmax_k(float* __restrict__ e) {
    int t = blockIdx.x;
    float* row = e + (size_t)t * L;
    int tid = threadIdx.x;
    float v0 = row[tid], v1 = row[tid + 256];
    float m = fmaxf(v0, v1);
#pragma unroll
    for (int off = 32; off > 0; off >>= 1) m = fmaxf(m, __shfl_xor(m, off));
    __shared__ float red[4];
    __shared__ float red2[4];
    int wid = tid >> 6, lane = tid & 63;
    if (lane == 0) red[wid] = m;
    __syncthreads();
    m = fmaxf(fmaxf(red[0], red[1]), fmaxf(red[2], red[3]));
    float e0 = __expf(v0 - m), e1 = __expf(v1 - m);
    float s = e0 + e1;
#pragma unroll
    for (int off = 32; off > 0; off >>= 1) s += __shfl_xor(s, off);
    if (lane == 0) red2[wid] = s;
    __syncthreads();
    s = red2[0] + red2[1] + red2[2] + red2[3];
    float inv = __fdividef(1.f, s);
    row[tid] = e0 * inv;
    row[tid + 256] = e1 * inv;
}

// ---------------- GRU scan: r6 structure + s_sleep poll backoff ----------
// 128 blocks x 256 threads. blocks [0,64): forward, [64,128): backward.
// Each block owns 8 h-indices (24 whh rows in registers, interleaved column
// layout => bank-conflict-free LDS matvec). h exchange via SELF-VALIDATING
// words (24-bit fixed point scale 2^22 + 8-bit step tag per u32). Order is
// the measured-optimal r6 ordering: out-store BEFORE tagged store; gi
// prefetch between store and poll; NOTHING between poll detection and the
// hS write. NEW: s_sleep(1) (~64cy) after each failed poll iteration —
// cuts poll issue rate ~8x to relieve L3 hot-line queueing (2048 pollers
// per 64B line otherwise); detection granularity cost <=64cy << 500cy RTT.
// Ping-pong parity; skew <= 1 step => tags never alias; 0xAA ws-poison
// can't match tags 1/2 => no memset needed.
__global__ __launch_bounds__(256) void gru_scan_k(
    const float* __restrict__ whh_f, const float* __restrict__ bhh_f,
    const float* __restrict__ whh_b, const float* __restrict__ bhh_b,
    const float* __restrict__ gi_f, const float* __restrict__ gi_b,
    float* __restrict__ out,
    unsigned* __restrict__ hstage)   // [2 dirs][2 parity][512] encoded u32
{
    int blk = blockIdx.x;
    int dir = blk >> 6;          // 0 fwd, 1 bwd
    int bi = blk & 63;
    int hbase = bi * 8;
    const float* whh = dir ? whh_b : whh_f;
    const float* bhh = dir ? bhh_b : bhh_f;
    const float* gi  = dir ? gi_b : gi_f;
    float* outBase = out + dir * HH;       // row stride 1024
    unsigned* stage = hstage + dir * 1024;

    __shared__ float hS[HH];
    __shared__ float ghS[24];

    int tid = threadIdx.x;
    int rr = tid >> 3, c8 = tid & 7;
    bool active = rr < 24;

    float4 wreg[16];
    float bhv = 0.f;
    if (active) {
        int g = rr >> 3, i = rr & 7;
        const float4* wrow = (const float4*)(whh + (size_t)(g * HH + hbase + i) * HH);
#pragma unroll
        for (int q = 0; q < 16; q++) wreg[q] = wrow[q * 8 + c8];
        if (c8 == 0) bhv = bhh[g * HH + hbase + i];
    }
    for (int j = tid; j < HH; j += 256) hS[j] = 0.f;

    float ir = 0.f, iz = 0.f, inn = 0.f;
    if (tid < 8) {
        int t0 = dir ? (L - 1) : 0;
        const float* git = gi + (size_t)t0 * (3 * HH);
        ir  = git[hbase + tid];
        iz  = git[HH + hbase + tid];
        inn = git[2 * HH + hbase + tid];
    }
    __syncthreads();

    const float ENC = 4194304.0f;            // 2^22
    const float DEC = 1.0f / 4194304.0f;

    for (int s = 0; s < L; s++) {
        int t = dir ? (L - 1 - s) : s;

        float acc = 0.f;
        if (active) {
            const float4* h4 = (const float4*)hS;
#pragma unroll
            for (int q = 0; q < 16; q++) {
                float4 hv = h4[q * 8 + c8];   // lanes 16B apart: all 32 banks
                acc += wreg[q].x * hv.x + wreg[q].y * hv.y
                     + wreg[q].z * hv.z + wreg[q].w * hv.w;
            }
            acc += __shfl_xor(acc, 1);
            acc += __shfl_xor(acc, 2);
            acc += __shfl_xor(acc, 4);
            if (c8 == 0) ghS[rr] = acc + bhv;
        }
        __syncthreads();

        if (tid < 8) {
            int i = tid, hg = hbase + i;
            float r = sigmoidf_fast(ir + ghS[i]);
            float z = sigmoidf_fast(iz + ghS[8 + i]);
            float n = tanhf_fast(inn + r * ghS[16 + i]);
            float hnew = (1.f - z) * n + z * hS[hg];
            outBase[(size_t)t * 1024 + hg] = hnew;   // full-precision output
            unsigned enc = ((unsigned)__float2int_rn(hnew * ENC) & 0x00FFFFFFu)
                         | ((unsigned)((s + 1) & 0xFF) << 24);
            __hip_atomic_store(stage + (s & 1) * 512 + hg, enc,
                               __ATOMIC_RELAXED, __HIP_MEMORY_SCOPE_AGENT);
        }

        if (s == L - 1) break;

        // prefetch next step's gi while waiting on data
        if (tid < 8) {
            int tn = dir ? (L - 2 - s) : (s + 1);
            const float* git = gi + (size_t)tn * (3 * HH);
            ir  = git[hbase + tid];
            iz  = git[HH + hbase + tid];
            inn = git[2 * HH + hbase + tid];
        }

        // poll the two words this thread consumes (data IS the flag),
        // with s_sleep backoff on miss to relieve L3 hot-line pressure
        {
            unsigned tag = (unsigned)((s + 1) & 0xFF);
            const unsigned* src = stage + (s & 1) * 512;
            unsigned e0 = 0, e1 = 0;
            bool g0 = false, g1 = false;
            while (true) {
                if (!g0) {
                    e0 = __hip_atomic_load(src + tid, __ATOMIC_RELAXED,
                                           __HIP_MEMORY_SCOPE_AGENT);
                    g0 = ((e0 >> 24) == tag);
                }
                if (!g1) {
                    e1 = __hip_atomic_load(src + tid + 256, __ATOMIC_RELAXED,
                                           __HIP_MEMORY_SCOPE_AGENT);
                    g1 = ((e1 >> 24) == tag);
                }
                if (g0 && g1) break;
                __builtin_amdgcn_s_sleep(1);
            }
            hS[tid]       = (float)(((int)(e0 << 8)) >> 8) * DEC;
            hS[tid + 256] = (float)(((int)(e1 << 8)) >> 8) * DEC;
        }
        __syncthreads();
    }
}

extern "C" void kernel_launch(void* const* d_in, const int* in_sizes, int n_in,
                              void* d_out, int out_size, void* d_ws, size_t ws_size,
                              hipStream_t stream) {
    const float* v     = (const float*)d_in[0];
    const float* w1    = (const float*)d_in[1];
    const float* b1    = (const float*)d_in[2];
    const float* w2    = (const float*)d_in[3];
    const float* b2    = (const float*)d_in[4];
    const float* wih_f = (const float*)d_in[5];
    const float* whh_f = (const float*)d_in[6];
    const float* bih_f = (const float*)d_in[7];
    const float* bhh_f = (const float*)d_in[8];
    const float* wih_b = (const float*)d_in[9];
    const float* whh_b = (const float*)d_in[10];
    const float* bih_b = (const float*)d_in[11];
    const float* bhh_b = (const float*)d_in[12];
    float* out = (float*)d_out;   // f32 [512, 1024]

    float* ws = (float*)d_ws;
    float* u   = ws;                 // 512*512
    float* w_  = ws + 262144;        // 512*512
    float* e   = ws + 524288;        // 512*512 (becomes a after softmax)
    float* c   = ws + 786432;        // 512*512
    float* gif = ws + 1572864;       // 512*1536
    float* gib = ws + 2359296;       // 512*1536
    unsigned* hstage = (unsigned*)(ws + 3145728);  // 2*2*512 u32 (no init needed)

    // u = v @ w1^T + b1 ; w = v @ w2^T + b2  (one launch, z selects)
    gemm2_k<1><<<dim3(8, 8, 2), 256, 0, stream>>>(v, w1, w2, b1, b2, u, w_,
                                                  512, 512, 512);

    // e[t,j] = sum_d tanh(u[j,d]+w[t,d]) v[j,d]
    attn_e_k<<<dim3(16, 32), 256, 0, stream>>>(u, w_, v, e);
    softmax_k<<<512, 256, 0, stream>>>(e);

    // c = a @ v
    gemm_k<0><<<dim3(8, 8), 256, 0, stream>>>(e, v, nullptr, c, 512, 512, 512);

    // gi = [v|c] @ wih^T + bih, both directions, concat fused into A-load
    gemm_gi_k<<<dim3(24, 8, 2), 256, 0, stream>>>(v, c, wih_f, wih_b,
                                                  bih_f, bih_b, gif, gib);

    gru_scan_k<<<128, 256, 0, stream>>>(whh_f, bhh_f, whh_b, bhh_b,
                                        gif, gib, out, hstage);
}